// Round 6
// baseline (4041.813 us; speedup 1.0000x reference)
//
#include <hip/hip_runtime.h>
#include <stdint.h>

#define B_    4096
#define D_    768
#define FUP   12288
#define FDN   12288
#define CONN  256
#define KTOP  64
#define CHUNK 1024            // phase-1 chunk
#define NCH   (B_ / CHUNK)
#define CH2   512             // phase-2 chunk (fits workspace with rev+Bsplit live)
#define NCH2  (B_ / CH2)
#define PDW   1024            // k_pd fu-window (3 MB fp32: fits 4 MB per-XCD L2)
#define NPW   (FUP / PDW)     // 12 windows (+1 dup bucket)

typedef short short8v __attribute__((ext_vector_type(8)));
typedef float f32x4  __attribute__((ext_vector_type(4)));

// ---------------------------------------------------------------- utilities

__device__ __forceinline__ unsigned fkey(float x) {
    unsigned u = __float_as_uint(x);
    return (u & 0x80000000u) ? ~u : (u | 0x80000000u);
}

// Block-wide top-64 select over vals[0..n) (LDS resident), exact jax
// tie-breaking (lowest index among equals at the threshold).
__device__ void topk64_block(const float* vals, int n, int* gidx, float* gval,
                             unsigned* hist, int* scratch)
{
    const int tid = threadIdx.x;
    if (tid == 0) { scratch[0] = KTOP; scratch[1] = 0; scratch[2] = 0; scratch[3] = 0; }
    for (int l = 24; l >= 0; l -= 8) {
        hist[tid] = 0;
        __syncthreads();
        unsigned prefix = (unsigned)scratch[1];
        unsigned hm = (l == 24) ? 0u : (0xFFFFFFFFu << (l + 8));
        for (int i = tid; i < n; i += 256) {
            unsigned key = fkey(vals[i]);
            if ((key & hm) == (prefix & hm)) atomicAdd(&hist[(key >> l) & 255], 1u);
        }
        __syncthreads();
        if (tid == 0) {
            int need = scratch[0];
            unsigned acc = 0;
            for (int b2 = 255; b2 >= 0; --b2) {
                unsigned h = hist[b2];
                if (acc + h >= (unsigned)need) {
                    scratch[1] = (int)(prefix | ((unsigned)b2 << l));
                    scratch[0] = need - (int)acc;
                    break;
                }
                acc += h;
            }
        }
        __syncthreads();
    }
    unsigned thresh = (unsigned)scratch[1];
    for (int i = tid; i < n; i += 256) {
        float v = vals[i];
        unsigned key = fkey(v);
        if (key > thresh) {
            int p = atomicAdd(&scratch[2], 1);
            gidx[p] = i; gval[p] = v;
        } else if (key == thresh) {
            int p = atomicAdd(&scratch[3], 1);
            if (p < 64) scratch[4 + p] = i;
        }
    }
    __syncthreads();
    if (tid == 0) {
        int cnt = scratch[2];
        int ne  = KTOP - cnt;
        int ec  = scratch[3] < 64 ? scratch[3] : 64;
        for (int a2 = 0; a2 < ne; ++a2) {
            int best = 0x7fffffff, bi = -1;
            for (int q = 0; q < ec; ++q) {
                int id = scratch[4 + q];
                if (id >= 0 && id < best) { best = id; bi = q; }
            }
            if (bi >= 0) {
                scratch[4 + bi] = -1;
                gidx[cnt + a2] = best; gval[cnt + a2] = vals[best];
            }
        }
    }
    __syncthreads();
}

// ---------------------------------------------------------------- kernels

__global__ void k_detect(const int* __restrict__ conn, int* mode) {
    if (blockIdx.x == 0 && threadIdx.x == 0) {
        int z = 1;
        for (int i = 1; i < 128; i += 2) z &= (conn[i] == 0);
        *mode = z;
    }
}

__device__ __forceinline__ int getconn(const int* c, size_t e, int mode) {
    return mode ? c[2 * e] : c[e];
}

__global__ void k_zero(unsigned* __restrict__ p, int n) {
    for (int i = blockIdx.x * blockDim.x + threadIdx.x; i < n;
         i += gridDim.x * blockDim.x)
        p[i] = 0u;
}

// in[R][Cc] -> out[Cc][R]
__global__ void k_transpose(const float* __restrict__ in, float* __restrict__ out,
                            int R, int Cc) {
    __shared__ float t[32][33];
    int x = blockIdx.x * 32 + threadIdx.x;
    int yb = blockIdx.y * 32;
    for (int j = threadIdx.y; j < 32; j += 8)
        t[j][threadIdx.x] = in[(size_t)(yb + j) * Cc + x];
    __syncthreads();
    int xo  = yb + threadIdx.x;
    int yb2 = blockIdx.x * 32;
    for (int j = threadIdx.y; j < 32; j += 8)
        out[(size_t)(yb2 + j) * R + xo] = t[threadIdx.x][j];
}

__global__ void k_precompute(const float* __restrict__ Wup, const float* __restrict__ Wdn,
                             const float* __restrict__ b_enc_up, const float* __restrict__ b_enc_down,
                             const float* __restrict__ b_dec_up, const float* __restrict__ b_dec_down,
                             float* __restrict__ bias_up, float* __restrict__ c_in,
                             float* __restrict__ c_out) {
    int wave = threadIdx.x >> 6, lane = threadIdx.x & 63;
    int f = blockIdx.x * 4 + wave;
    if (f >= FUP) return;
    const float* ru = Wup + (size_t)f * D_;
    const float* rd = Wdn + (size_t)f * D_;
    float s1 = 0.f, s2 = 0.f, s3 = 0.f;
    for (int d = lane; d < D_; d += 64) {
        float bu = b_dec_up[d], bd = b_dec_down[d];
        s1 += ru[d] * bu;
        float w = rd[d];
        s2 += w * bu;
        s3 += w * bd;
    }
    for (int m = 32; m; m >>= 1) {
        s1 += __shfl_xor(s1, m);
        s2 += __shfl_xor(s2, m);
        s3 += __shfl_xor(s3, m);
    }
    if (!lane) {
        bias_up[f] = b_enc_up[f] - s1;
        c_in[f]  = s2;
        c_out[f] = b_enc_down[f] - s3;
    }
}

// fp32 [R][768] -> 3 bf16 planes [R][768] (exact hi+mid+lo split, RNE).
__device__ __forceinline__ unsigned short bf16rne(float f) {
    unsigned u = __float_as_uint(f);
    unsigned r = u + 0x7FFFu + ((u >> 16) & 1u);
    return (unsigned short)(r >> 16);
}
__global__ __launch_bounds__(256) void k_split3(const float* __restrict__ in,
                                                unsigned short* __restrict__ out,
                                                int R) {
    const size_t plane = (size_t)R * D_;
    size_t base = ((size_t)blockIdx.x * 256 + threadIdx.x) * 8;
    float v[8];
    *(float4*)&v[0] = *(const float4*)(in + base);
    *(float4*)&v[4] = *(const float4*)(in + base + 4);
    unsigned short h[8], m[8], l[8];
#pragma unroll
    for (int i = 0; i < 8; ++i) {
        float f = v[i];
        unsigned short hb = bf16rne(f);
        float hf = __uint_as_float((unsigned)hb << 16);
        float r1 = f - hf;
        unsigned short mb = bf16rne(r1);
        float mf = __uint_as_float((unsigned)mb << 16);
        float r2 = r1 - mf;
        unsigned short lb = bf16rne(r2);
        h[i] = hb; m[i] = mb; l[i] = lb;
    }
    *(short8v*)(out + base)             = *(short8v*)h;
    *(short8v*)(out + plane + base)     = *(short8v*)m;
    *(short8v*)(out + 2 * plane + base) = *(short8v*)l;
}

// C[M,N] = A[M,K=768] @ B[N,K]^T (+bias)(+relu) via 3-way bf16-split MFMA.
// 6 products (hh, hm, mh, mm, hl, lh): dropped terms ~2^-24 => fp32-grade.
// 128x128 tile, 4 waves (2x2), each wave 64x64 = 4x4 frags of 16x16x32.
// Staging via global_load_lds(16B): linear LDS slots, inverse-XOR source,
// XOR on ds_read (rule #21: both-sides-or-neither). f(r) = (r>>1)&3 on the
// 16B k-chunk index -> stride-64B frag reads become 2-way aliased (free).
#define GBM 128
#define GBN 128
#define GBK 32

__device__ __forceinline__ void gld16(const void* g, void* l) {
    __builtin_amdgcn_global_load_lds(
        (const __attribute__((address_space(1))) unsigned int*)g,
        (__attribute__((address_space(3))) unsigned int*)l, 16, 0, 0);
}

__global__ __launch_bounds__(256, 2) void k_gemm_mfma(
    const unsigned short* __restrict__ Asp, const unsigned short* __restrict__ Bsp,
    float* __restrict__ C, const float* __restrict__ bias,
    int M, int N, int doRelu)
{
    // 3072 slots x 16B = 48 KB: A planes [3][128][4 chunks] then B
    __shared__ __attribute__((aligned(16))) unsigned short L[3072 * 8];
    const int tid = threadIdx.x;
    // XCD-aware bijective block remap (nwg % 8 == 0 for all our grids)
    const int nbx = gridDim.x;
    const int nwg = nbx * gridDim.y;
    int id = blockIdx.y * nbx + blockIdx.x;
    if ((nwg & 7) == 0) id = (id & 7) * (nwg >> 3) + (id >> 3);
    const int bm = (id / nbx) * GBM, bn = (id % nbx) * GBN;

    const int wid = tid >> 6, lane = tid & 63;
    const int wm = (wid >> 1) * 64, wn = (wid & 1) * 64;
    const int l15 = lane & 15, g4 = lane >> 4;
    const size_t psA = (size_t)M * D_, psB = (size_t)N * D_;

    // per-lane staging descriptors (k-invariant): wave w owns slots [768w,768w+768)
    const unsigned short* gsrc[12];
    unsigned short* ldst[12];
#pragma unroll
    for (int q2 = 0; q2 < 12; ++q2) {
        int s  = wid * 768 + q2 * 64 + lane;
        int isB = (s >= 1536);
        int sl = isB ? (s - 1536) : s;
        int p  = sl >> 9;          // plane
        int rem = sl & 511;
        int r  = rem >> 2;         // tile row
        int cs = rem & 3;          // swizzled 16B k-chunk slot
        int c  = cs ^ ((r >> 1) & 3);   // source k-chunk (inverse swizzle)
        const unsigned short* bp = isB ? Bsp : Asp;
        size_t ps = isB ? psB : psA;
        int row = (isB ? bn : bm) + r;
        gsrc[q2] = bp + (size_t)p * ps + (size_t)row * D_ + c * 8;
        ldst[q2] = L + (wid * 768 + q2 * 64) * 8;   // slot*8 shorts (=16B)
    }
    // frag ds_read bases (shorts); swizzle const per lane: f((R+16i))==f(R)
    const int fA = ((wm + l15) >> 1) & 3;
    const int fB = ((wn + l15) >> 1) & 3;
    const unsigned short* aB = L + (wm + l15) * 32 + ((g4 ^ fA) * 8);
    const unsigned short* bB = L + 1536 * 8 + (wn + l15) * 32 + ((g4 ^ fB) * 8);

    f32x4 acc[4][4] = {};
    for (int k0 = 0; k0 < D_; k0 += GBK) {
        __syncthreads();               // prev-iter reads done before overwrite
#pragma unroll
        for (int q2 = 0; q2 < 12; ++q2)
            gld16(gsrc[q2] + k0, ldst[q2]);
        __syncthreads();               // drains vmcnt -> LDS tile ready
        short8v af[3][4], bf[3][4];
#pragma unroll
        for (int i = 0; i < 4; ++i)
#pragma unroll
            for (int p = 0; p < 3; ++p) {
                af[p][i] = *(const short8v*)(aB + p * 4096 + i * 512);
                bf[p][i] = *(const short8v*)(bB + p * 4096 + i * 512);
            }
#pragma unroll
        for (int i = 0; i < 4; ++i)
#pragma unroll
            for (int j = 0; j < 4; ++j) {
                acc[i][j] = __builtin_amdgcn_mfma_f32_16x16x32_bf16(af[0][i], bf[0][j], acc[i][j], 0, 0, 0);
                acc[i][j] = __builtin_amdgcn_mfma_f32_16x16x32_bf16(af[0][i], bf[1][j], acc[i][j], 0, 0, 0);
                acc[i][j] = __builtin_amdgcn_mfma_f32_16x16x32_bf16(af[1][i], bf[0][j], acc[i][j], 0, 0, 0);
                acc[i][j] = __builtin_amdgcn_mfma_f32_16x16x32_bf16(af[1][i], bf[1][j], acc[i][j], 0, 0, 0);
                acc[i][j] = __builtin_amdgcn_mfma_f32_16x16x32_bf16(af[0][i], bf[2][j], acc[i][j], 0, 0, 0);
                acc[i][j] = __builtin_amdgcn_mfma_f32_16x16x32_bf16(af[2][i], bf[0][j], acc[i][j], 0, 0, 0);
            }
    }
    // C/D layout: col = lane&15, row = (lane>>4)*4 + reg   [m89-verified]
#pragma unroll
    for (int i = 0; i < 4; ++i) {
        int gr0 = bm + wm + i * 16 + (lane >> 4) * 4;
#pragma unroll
        for (int j = 0; j < 4; ++j) {
            int gc = bn + wn + j * 16 + l15;
            float bv = bias ? bias[gc] : 0.f;
#pragma unroll
            for (int q = 0; q < 4; ++q) {
                float v = acc[i][j][q] + bv;
                if (doRelu) v = fmaxf(v, 0.f);
                C[(size_t)(gr0 + q) * N + gc] = v;
            }
        }
    }
}

__global__ __launch_bounds__(256) void k_topk_up(const float* __restrict__ big,
                                                 int* __restrict__ up_idx,
                                                 float* __restrict__ up_val) {
    __shared__ __attribute__((aligned(16))) float row[FUP];
    __shared__ unsigned hist[256];
    __shared__ int scratch[68];
    int b = blockIdx.x;
    const float4* s4 = (const float4*)(big + (size_t)b * FUP);
    float4* r4 = (float4*)row;
    for (int i = threadIdx.x; i < FUP / 4; i += 256) r4[i] = s4[i];
    __syncthreads();
    topk64_block(row, FUP, up_idx + b * 64, up_val + b * 64, hist, scratch);
}

// Counting-sort each fd's 256 connections into NPW fu-window buckets plus a
// dup bucket (index NPW). Output: ent_fu/ent_c (window-sorted per fd) and
// per-fd bucket offsets woff[fd][NPW+2] (last = 256).
__global__ __launch_bounds__(256) void k_sortwin(
    const int* __restrict__ conn, const int* __restrict__ mode_p,
    unsigned short* __restrict__ ent_fu, unsigned char* __restrict__ ent_c,
    unsigned short* __restrict__ woff)
{
    __shared__ int crow[CONN];
    __shared__ int cnt[NPW + 1];
    __shared__ int base[NPW + 1];
    __shared__ int cur[NPW + 1];
    int fd = blockIdx.x, tid = threadIdx.x;
    int mode = *mode_p;
    crow[tid] = getconn(conn, (size_t)fd * CONN + tid, mode);
    if (tid <= NPW) cnt[tid] = 0;
    __syncthreads();
    int fu = crow[tid];
    bool dup = false;
    for (int q = 0; q < tid; ++q) dup |= (crow[q] == fu);
    int win = dup ? NPW : (fu / PDW);
    atomicAdd(&cnt[win], 1);
    __syncthreads();
    if (tid == 0) {
        int run = 0;
        for (int i = 0; i <= NPW; ++i) { base[i] = run; run += cnt[i]; }
    }
    __syncthreads();
    if (tid <= NPW) {
        woff[fd * (NPW + 2) + tid] = (unsigned short)base[tid];
        cur[tid] = base[tid];
    }
    if (tid == 0) woff[fd * (NPW + 2) + NPW + 1] = (unsigned short)CONN;
    __syncthreads();
    int pos = atomicAdd(&cur[win], 1);
    ent_fu[(size_t)fd * CONN + pos] = (unsigned short)fu;
    ent_c[(size_t)fd * CONN + pos]  = (unsigned char)tid;
}

// pd[fd,c] = W_enc_down[fd]·W_dec_upT[fu]  — register-direct, no LDS/barrier.
// One 16-lane group per fd (16 fds/block); Wdn row in 12 float4 regs; then a
// sequential sweep over that fd's window entries: 12 independent L2 loads +
// 4 accumulator chains per entry. Window is the slow grid dim (WduT window
// stays L2-resident, the k_pd2 property). L2-read floor ~272 us; k_pd2's
// barrier-staged version ran 478 us at 57% of L2 peak.
__global__ __launch_bounds__(256) void k_pd5(
    const float* __restrict__ Wdn, const float* __restrict__ WduT,
    const unsigned short* __restrict__ ent_fu, const unsigned char* __restrict__ ent_c,
    const unsigned short* __restrict__ woff, float* __restrict__ pd)
{
    const int win = blockIdx.y, tid = threadIdx.x;
    const int grp = tid >> 4, gi = tid & 15;
    const int fd = blockIdx.x * 16 + grp;
    const size_t ebase = (size_t)fd * CONN;
    if (win == NPW) {           // dup bucket: masked entries contribute 0
        int s = woff[fd * (NPW + 2) + NPW];
        for (int t = s + gi; t < CONN; t += 16)
            pd[ebase + ent_c[ebase + t]] = 0.f;
        return;
    }
    const int s = woff[fd * (NPW + 2) + win];
    const int e = woff[fd * (NPW + 2) + win + 1];
    if (s == e) return;
    const float* wd = Wdn + (size_t)fd * D_;
    float4 wr[12];
#pragma unroll
    for (int j = 0; j < 12; ++j)
        wr[j] = *(const float4*)(wd + gi * 4 + j * 64);
    for (int t = s; t < e; ++t) {
        int fu = ent_fu[ebase + t];
        const float* wu = WduT + (size_t)fu * D_;
        float4 u[12];
#pragma unroll
        for (int j = 0; j < 12; ++j)
            u[j] = *(const float4*)(wu + gi * 4 + j * 64);
        float s0 = 0.f, s1 = 0.f, s2 = 0.f, s3 = 0.f;
#pragma unroll
        for (int j = 0; j < 12; j += 4) {
            s0 = fmaf(u[j+0].x, wr[j+0].x, s0); s0 = fmaf(u[j+0].y, wr[j+0].y, s0);
            s0 = fmaf(u[j+0].z, wr[j+0].z, s0); s0 = fmaf(u[j+0].w, wr[j+0].w, s0);
            s1 = fmaf(u[j+1].x, wr[j+1].x, s1); s1 = fmaf(u[j+1].y, wr[j+1].y, s1);
            s1 = fmaf(u[j+1].z, wr[j+1].z, s1); s1 = fmaf(u[j+1].w, wr[j+1].w, s1);
            s2 = fmaf(u[j+2].x, wr[j+2].x, s2); s2 = fmaf(u[j+2].y, wr[j+2].y, s2);
            s2 = fmaf(u[j+2].z, wr[j+2].z, s2); s2 = fmaf(u[j+2].w, wr[j+2].w, s2);
            s3 = fmaf(u[j+3].x, wr[j+3].x, s3); s3 = fmaf(u[j+3].y, wr[j+3].y, s3);
            s3 = fmaf(u[j+3].z, wr[j+3].z, s3); s3 = fmaf(u[j+3].w, wr[j+3].w, s3);
        }
        float sacc = (s0 + s1) + (s2 + s3);
#pragma unroll
        for (int m = 1; m < 16; m <<= 1) sacc += __shfl_xor(sacc, m);
        if (gi == 0)
            pd[ebase + ent_c[ebase + t]] = sacc;
    }
}

__global__ void k_hist(const int* __restrict__ conn, const int* __restrict__ mode_p,
                       unsigned* __restrict__ counts, int total) {
    int mode = *mode_p;
    for (int e = blockIdx.x * blockDim.x + threadIdx.x; e < total;
         e += gridDim.x * blockDim.x)
        atomicAdd(&counts[getconn(conn, (size_t)e, mode)], 1u);
}

__global__ void k_scan(const unsigned* __restrict__ counts,
                       unsigned* __restrict__ offsets, unsigned* __restrict__ cursor) {
    __shared__ unsigned sums[256];
    int tid = threadIdx.x;
    const int CH = FUP / 256;   // 48
    unsigned local = 0;
    for (int i = 0; i < CH; ++i) local += counts[tid * CH + i];
    sums[tid] = local;
    __syncthreads();
    for (int off = 1; off < 256; off <<= 1) {
        unsigned v = 0;
        if (tid >= off) v = sums[tid - off];
        __syncthreads();
        sums[tid] += v;
        __syncthreads();
    }
    unsigned run = (tid == 0) ? 0u : sums[tid - 1];
    for (int i = 0; i < CH; ++i) {
        int idx = tid * CH + i;
        offsets[idx] = run;
        cursor[idx]  = run;
        run += counts[idx];
    }
    if (tid == 255) offsets[FUP] = run;
}

__global__ void k_scatter(const int* __restrict__ conn, const int* __restrict__ mode_p,
                          const float* __restrict__ pd, unsigned* __restrict__ cursor,
                          unsigned short* __restrict__ rev_fd, float* __restrict__ rev_w,
                          int total) {
    int mode = *mode_p;
    for (int e = blockIdx.x * blockDim.x + threadIdx.x; e < total;
         e += gridDim.x * blockDim.x) {
        int fu = getconn(conn, (size_t)e, mode);
        unsigned pos = atomicAdd(&cursor[fu], 1u);
        rev_fd[pos] = (unsigned short)(e >> 8);   // fd = e / CONN
        rev_w[pos]  = pd[e];
    }
}

// per-batch-row: contributions scatter + combine + top-64 of approx
__global__ __launch_bounds__(256) void k_down(
    const float* __restrict__ big /*approx0*/, const float* __restrict__ ln_scale,
    const float* __restrict__ c_in, const float* __restrict__ c_out,
    const int* __restrict__ up_idx, const float* __restrict__ up_val,
    const unsigned* __restrict__ offsets, const unsigned short* __restrict__ rev_fd,
    const float* __restrict__ rev_w, int* __restrict__ down_idx,
    float* __restrict__ down_val)
{
    __shared__ __attribute__((aligned(16))) float contrib[FDN];
    __shared__ unsigned hist[256];
    __shared__ int scratch[68];
    int b = blockIdx.x, tid = threadIdx.x;
    float4* c4 = (float4*)contrib;
    for (int i = tid; i < FDN / 4; i += 256) c4[i] = make_float4(0.f, 0.f, 0.f, 0.f);
    __syncthreads();
    for (int j = 0; j < KTOP; ++j) {
        int fu = up_idx[b * 64 + j];
        float v = up_val[b * 64 + j];
        unsigned s = offsets[fu], e = offsets[fu + 1];
        for (unsigned t = s + tid; t < e; t += 256)
            atomicAdd(&contrib[rev_fd[t]], v * rev_w[t]);
    }
    __syncthreads();
    float ls = ln_scale[b];
    const float* ap = big + (size_t)b * FDN;
    for (int i = tid; i < FDN; i += 256)
        contrib[i] = (ap[i] + contrib[i] + c_in[i]) / ls + c_out[i];
    __syncthreads();
    topk64_block(contrib, FDN, down_idx + b * 64, down_val + b * 64, hist, scratch);
}

__global__ __launch_bounds__(256) void k_decode(
    const int* __restrict__ down_idx, const float* __restrict__ down_val,
    const float* __restrict__ WddT, const float* __restrict__ b_dec_down,
    float* __restrict__ out)
{
    __shared__ int fidx[64];
    __shared__ float fval[64];
    int b = blockIdx.x, tid = threadIdx.x;
    if (tid < 64) { fidx[tid] = down_idx[b * 64 + tid]; fval[tid] = down_val[b * 64 + tid]; }
    __syncthreads();
    float a0 = b_dec_down[tid], a1 = b_dec_down[tid + 256], a2 = b_dec_down[tid + 512];
    for (int j = 0; j < 64; ++j) {
        const float* r = WddT + (size_t)fidx[j] * D_;
        float v = fval[j];
        a0 += v * r[tid];
        a1 += v * r[tid + 256];
        a2 += v * r[tid + 512];
    }
    float* o = out + (size_t)b * D_;
    o[tid] = a0; o[tid + 256] = a1; o[tid + 512] = a2;
}

// ---------------------------------------------------------------- launch

extern "C" void kernel_launch(void* const* d_in, const int* in_sizes, int n_in,
                              void* d_out, int out_size, void* d_ws, size_t ws_size,
                              hipStream_t stream)
{
    const float* initial_acts = (const float*)d_in[0];
    const float* x_up         = (const float*)d_in[1];
    const float* ln_scale     = (const float*)d_in[2];
    const float* W_enc_up     = (const float*)d_in[3];
    const float* b_enc_up     = (const float*)d_in[4];
    const float* b_dec_up     = (const float*)d_in[5];
    const float* W_dec_up     = (const float*)d_in[6];
    const float* W_enc_down   = (const float*)d_in[7];
    const float* b_enc_down   = (const float*)d_in[8];
    const float* b_dec_down   = (const float*)d_in[9];
    const float* W_dec_down   = (const float*)d_in[10];
    const int*   conn         = (const int*)d_in[11];
    float* out = (float*)d_out;

    // ---- workspace layout (~132.7 MB of 128 MiB = 134.2 MB) ----
    // region 0 (bigU, 50,331,648 B): phase1 big[1024x12288] f32; then
    //   pd(12.58M)+ent_fu(6.29M)+ent_c(3.15M)+woff(0.34M); then phase2 big[512x12288]
    // region Bsplit (56,623,104 B): phase1 Wup 3xbf16 planes; then WduT f32
    //   (37.7M); then Wdn 3xbf16 planes; then WddT f32
    // Asplit1 (phase1, 4.72M) overlaps rev_w (rev_w written only after phase1)
    char* w = (char*)d_ws;
    float*          big      = (float*)(w);
    float*          pd       = (float*)(w);                          // after phase1
    unsigned short* ent_fu   = (unsigned short*)(w + 12582912);
    unsigned char*  ent_c    = (unsigned char*) (w + 18874368);
    unsigned short* woff     = (unsigned short*)(w + 22020096);      // ends 22,364,160
    unsigned short* Bsplit   = (unsigned short*)(w + 50331648);      // 56,623,104 B
    float*          Wt       = (float*)(w + 50331648);               // alias (WduT/WddT)
    float*          rev_w    = (float*)(w + 106954752);              // 12,582,912 B
    unsigned short* Asplit1  = (unsigned short*)(w + 106954752);     // phase1 alias
    unsigned short* rev_fd   = (unsigned short*)(w + 119537664);     // 6,291,456 B
    unsigned short* Asplit2  = (unsigned short*)(w + 125829120);     // 2,359,296 B
    int*            up_idx   = (int*)  (w + 128188416);              // 1 MiB
    float*          up_val   = (float*)(w + 129236992);              // 1 MiB
    int*            down_idx = (int*)  (w + 130285568);              // 1 MiB
    float*          down_val = (float*)(w + 131334144);              // 1 MiB
    unsigned*       offsets  = (unsigned*)(w + 132382720);           // 64 KiB
    unsigned*       cursor   = (unsigned*)(w + 132448256);           // 64 KiB
    unsigned*       counts   = (unsigned*)(w + 132513792);           // 64 KiB
    float*          bias_up  = (float*)(w + 132579328);              // 48 KiB
    float*          c_in     = (float*)(w + 132628480);              // 48 KiB
    float*          c_out    = (float*)(w + 132677632);              // 48 KiB
    int*            mode_p   = (int*)  (w + 132726784);
    // ends ~132,726,848 B

    const int total_conn = FDN * CONN;
    dim3 tb(32, 8);

    k_detect<<<1, 64, 0, stream>>>(conn, mode_p);
    k_precompute<<<FUP / 4, 256, 0, stream>>>(W_enc_up, W_enc_down, b_enc_up, b_enc_down,
                                              b_dec_up, b_dec_down, bias_up, c_in, c_out);
    // phase 1: pre_up = relu(x_up @ W_enc_up^T + bias_up), then top-64, per chunk
    k_split3<<<FUP * D_ / 2048, 256, 0, stream>>>(W_enc_up, Bsplit, FUP);
    for (int c = 0; c < NCH; ++c) {
        k_split3<<<CHUNK * D_ / 2048, 256, 0, stream>>>(x_up + (size_t)c * CHUNK * D_,
                                                        Asplit1, CHUNK);
        k_gemm_mfma<<<dim3(FUP / GBN, CHUNK / GBM), 256, 0, stream>>>(
            Asplit1, Bsplit, big, bias_up, CHUNK, FUP, 1);
        k_topk_up<<<CHUNK, 256, 0, stream>>>(big, up_idx + (size_t)c * CHUNK * 64,
                                             up_val + (size_t)c * CHUNK * 64);
    }
    // WduT into Bsplit region (Wup splits dead); ent into big region (big dead)
    k_transpose<<<dim3(FUP / 32, D_ / 32), tb, 0, stream>>>(W_dec_up, Wt, D_, FUP);
    k_sortwin<<<FDN, 256, 0, stream>>>(conn, mode_p, ent_fu, ent_c, woff);
    k_pd5<<<dim3(FDN / 16, NPW + 1), 256, 0, stream>>>(W_enc_down, Wt, ent_fu, ent_c,
                                                       woff, pd);
    k_zero<<<48, 256, 0, stream>>>(counts, FUP);
    k_hist<<<4096, 256, 0, stream>>>(conn, mode_p, counts, total_conn);
    k_scan<<<1, 256, 0, stream>>>(counts, offsets, cursor);
    k_scatter<<<4096, 256, 0, stream>>>(conn, mode_p, pd, cursor, rev_fd, rev_w, total_conn);
    // phase 2: approx0 = initial_acts @ W_enc_down^T, combine + top-64, per CH2 chunk
    k_split3<<<FDN * D_ / 2048, 256, 0, stream>>>(W_enc_down, Bsplit, FDN);
    for (int c = 0; c < NCH2; ++c) {
        k_split3<<<CH2 * D_ / 2048, 256, 0, stream>>>(initial_acts + (size_t)c * CH2 * D_,
                                                      Asplit2, CH2);
        k_gemm_mfma<<<dim3(FDN / GBN, CH2 / GBM), 256, 0, stream>>>(
            Asplit2, Bsplit, big, nullptr, CH2, FDN, 0);
        k_down<<<CH2, 256, 0, stream>>>(big, ln_scale + (size_t)c * CH2, c_in, c_out,
                                        up_idx + (size_t)c * CH2 * 64,
                                        up_val + (size_t)c * CH2 * 64,
                                        offsets, rev_fd, rev_w,
                                        down_idx + (size_t)c * CH2 * 64,
                                        down_val + (size_t)c * CH2 * 64);
    }
    // WddT into Bsplit region (Wdn splits dead after last GEMM2)
    k_transpose<<<dim3(FDN / 32, D_ / 32), tb, 0, stream>>>(W_dec_down, Wt, D_, FDN);
    k_decode<<<B_, 256, 0, stream>>>(down_idx, down_val, Wt, b_dec_down, out);
}

// Round 7
// 3325.038 us; speedup vs baseline: 1.2156x; 1.2156x over previous
//
#include <hip/hip_runtime.h>
#include <stdint.h>

#define B_    4096
#define D_    768
#define FUP   12288
#define FDN   12288
#define CONN  256
#define KTOP  64
#define CHUNK 1024            // phase-1 chunk
#define NCH   (B_ / CHUNK)
#define CH2   512             // phase-2 chunk (fits workspace with rev+Bsplit live)
#define NCH2  (B_ / CH2)
#define PDW   1024            // k_pd fu-window (3 MB fp32: fits 4 MB per-XCD L2)
#define NPW   (FUP / PDW)     // 12 windows (+1 dup bucket)

typedef short short8v __attribute__((ext_vector_type(8)));
typedef float f32x4  __attribute__((ext_vector_type(4)));

// ---------------------------------------------------------------- utilities

__device__ __forceinline__ unsigned fkey(float x) {
    unsigned u = __float_as_uint(x);
    return (u & 0x80000000u) ? ~u : (u | 0x80000000u);
}

// Block-wide top-64 select over vals[0..n) (LDS resident), exact jax
// tie-breaking (lowest index among equals at the threshold).
// Bin-select is wave-parallel (suffix scan via shfl, ~100cyc) instead of the
// old 256-iter serial loop on tid0 (~3K cyc/pass) -- bit-identical result:
// chosen bin b* is the unique one with S(b*) < need <= T(b*).
__device__ void topk64_block(const float* vals, int n, int* gidx, float* gval,
                             unsigned* hist, int* scratch)
{
    const int tid = threadIdx.x;
    const int ln = tid & 63, wv = tid >> 6;
    if (tid == 0) { scratch[0] = KTOP; scratch[1] = 0; scratch[2] = 0; scratch[3] = 0; }
    for (int l = 24; l >= 0; l -= 8) {
        hist[tid] = 0;
        __syncthreads();
        unsigned prefix = (unsigned)scratch[1];
        int need = scratch[0];
        unsigned hm = (l == 24) ? 0u : (0xFFFFFFFFu << (l + 8));
        for (int i = tid; i < n; i += 256) {
            unsigned key = fkey(vals[i]);
            if ((key & hm) == (prefix & hm)) atomicAdd(&hist[(key >> l) & 255], 1u);
        }
        __syncthreads();
        unsigned hown = hist[tid];
        // inclusive suffix scan within wave (bins tid..(64*wv+63)), no barrier
        unsigned x = hown;
#pragma unroll
        for (int off = 1; off < 64; off <<= 1) {
            int sl = ln + off;
            unsigned v = __shfl(x, sl < 64 ? sl : ln);
            x += (sl < 64) ? v : 0u;
        }
        if (ln == 0) ((unsigned*)scratch)[4 + wv] = x;   // wave total
        __syncthreads();
        unsigned offw = 0;
        for (int w2 = wv + 1; w2 < 4; ++w2) offw += ((unsigned*)scratch)[4 + w2];
        unsigned T = x + offw;          // count of keys in bins >= tid
        unsigned S = T - hown;          // count of keys in bins >  tid
        if (S < (unsigned)need && T >= (unsigned)need) {
            scratch[1] = (int)(prefix | ((unsigned)tid << l));
            scratch[0] = need - (int)S;
        }
        __syncthreads();
    }
    unsigned thresh = (unsigned)scratch[1];
    for (int i = tid; i < n; i += 256) {
        float v = vals[i];
        unsigned key = fkey(v);
        if (key > thresh) {
            int p = atomicAdd(&scratch[2], 1);
            gidx[p] = i; gval[p] = v;
        } else if (key == thresh) {
            int p = atomicAdd(&scratch[3], 1);
            if (p < 64) scratch[4 + p] = i;
        }
    }
    __syncthreads();
    if (tid == 0) {
        int cnt = scratch[2];
        int ne  = KTOP - cnt;
        int ec  = scratch[3] < 64 ? scratch[3] : 64;
        for (int a2 = 0; a2 < ne; ++a2) {
            int best = 0x7fffffff, bi = -1;
            for (int q = 0; q < ec; ++q) {
                int id = scratch[4 + q];
                if (id >= 0 && id < best) { best = id; bi = q; }
            }
            if (bi >= 0) {
                scratch[4 + bi] = -1;
                gidx[cnt + a2] = best; gval[cnt + a2] = vals[best];
            }
        }
    }
    __syncthreads();
}

// ---------------------------------------------------------------- kernels

__global__ void k_detect(const int* __restrict__ conn, int* mode) {
    if (blockIdx.x == 0 && threadIdx.x == 0) {
        int z = 1;
        for (int i = 1; i < 128; i += 2) z &= (conn[i] == 0);
        *mode = z;
    }
}

__device__ __forceinline__ int getconn(const int* c, size_t e, int mode) {
    return mode ? c[2 * e] : c[e];
}

__global__ void k_zero(unsigned* __restrict__ p, int n) {
    for (int i = blockIdx.x * blockDim.x + threadIdx.x; i < n;
         i += gridDim.x * blockDim.x)
        p[i] = 0u;
}

// in[R][Cc] -> out[Cc][R]
__global__ void k_transpose(const float* __restrict__ in, float* __restrict__ out,
                            int R, int Cc) {
    __shared__ float t[32][33];
    int x = blockIdx.x * 32 + threadIdx.x;
    int yb = blockIdx.y * 32;
    for (int j = threadIdx.y; j < 32; j += 8)
        t[j][threadIdx.x] = in[(size_t)(yb + j) * Cc + x];
    __syncthreads();
    int xo  = yb + threadIdx.x;
    int yb2 = blockIdx.x * 32;
    for (int j = threadIdx.y; j < 32; j += 8)
        out[(size_t)(yb2 + j) * R + xo] = t[threadIdx.x][j];
}

__global__ void k_precompute(const float* __restrict__ Wup, const float* __restrict__ Wdn,
                             const float* __restrict__ b_enc_up, const float* __restrict__ b_enc_down,
                             const float* __restrict__ b_dec_up, const float* __restrict__ b_dec_down,
                             float* __restrict__ bias_up, float* __restrict__ c_in,
                             float* __restrict__ c_out) {
    int wave = threadIdx.x >> 6, lane = threadIdx.x & 63;
    int f = blockIdx.x * 4 + wave;
    if (f >= FUP) return;
    const float* ru = Wup + (size_t)f * D_;
    const float* rd = Wdn + (size_t)f * D_;
    float s1 = 0.f, s2 = 0.f, s3 = 0.f;
    for (int d = lane; d < D_; d += 64) {
        float bu = b_dec_up[d], bd = b_dec_down[d];
        s1 += ru[d] * bu;
        float w = rd[d];
        s2 += w * bu;
        s3 += w * bd;
    }
    for (int m = 32; m; m >>= 1) {
        s1 += __shfl_xor(s1, m);
        s2 += __shfl_xor(s2, m);
        s3 += __shfl_xor(s3, m);
    }
    if (!lane) {
        bias_up[f] = b_enc_up[f] - s1;
        c_in[f]  = s2;
        c_out[f] = b_enc_down[f] - s3;
    }
}

// fp32 [R][768] -> 3 bf16 planes [R][768] (exact hi+mid+lo split, RNE).
__device__ __forceinline__ unsigned short bf16rne(float f) {
    unsigned u = __float_as_uint(f);
    unsigned r = u + 0x7FFFu + ((u >> 16) & 1u);
    return (unsigned short)(r >> 16);
}
__global__ __launch_bounds__(256) void k_split3(const float* __restrict__ in,
                                                unsigned short* __restrict__ out,
                                                int R) {
    const size_t plane = (size_t)R * D_;
    size_t base = ((size_t)blockIdx.x * 256 + threadIdx.x) * 8;
    float v[8];
    *(float4*)&v[0] = *(const float4*)(in + base);
    *(float4*)&v[4] = *(const float4*)(in + base + 4);
    unsigned short h[8], m[8], l[8];
#pragma unroll
    for (int i = 0; i < 8; ++i) {
        float f = v[i];
        unsigned short hb = bf16rne(f);
        float hf = __uint_as_float((unsigned)hb << 16);
        float r1 = f - hf;
        unsigned short mb = bf16rne(r1);
        float mf = __uint_as_float((unsigned)mb << 16);
        float r2 = r1 - mf;
        unsigned short lb = bf16rne(r2);
        h[i] = hb; m[i] = mb; l[i] = lb;
    }
    *(short8v*)(out + base)             = *(short8v*)h;
    *(short8v*)(out + plane + base)     = *(short8v*)m;
    *(short8v*)(out + 2 * plane + base) = *(short8v*)l;
}

// C[M,N] = A[M,K=768] @ B[N,K]^T (+bias)(+relu) via 3-way bf16-split MFMA.
// 6 products (hh, hm, mh, mm, hl, lh): dropped terms ~2^-24 => fp32-grade.
// 128x128 tile, 4 waves (2x2), each wave 64x64 = 4x4 frags of 16x16x32.
// Staging via global_load_lds(16B): linear LDS slots, inverse-XOR source,
// XOR on ds_read (rule #21: both-sides-or-neither). f(r) = (r>>1)&3 on the
// 16B k-chunk index -> stride-64B frag reads become 2-way aliased (free).
#define GBM 128
#define GBN 128
#define GBK 32

__device__ __forceinline__ void gld16(const void* g, void* l) {
    __builtin_amdgcn_global_load_lds(
        (const __attribute__((address_space(1))) unsigned int*)g,
        (__attribute__((address_space(3))) unsigned int*)l, 16, 0, 0);
}

__global__ __launch_bounds__(256, 2) void k_gemm_mfma(
    const unsigned short* __restrict__ Asp, const unsigned short* __restrict__ Bsp,
    float* __restrict__ C, const float* __restrict__ bias,
    int M, int N, int doRelu)
{
    // 3072 slots x 16B = 48 KB: A planes [3][128][4 chunks] then B
    __shared__ __attribute__((aligned(16))) unsigned short L[3072 * 8];
    const int tid = threadIdx.x;
    // XCD-aware bijective block remap (nwg % 8 == 0 for all our grids)
    const int nbx = gridDim.x;
    const int nwg = nbx * gridDim.y;
    int id = blockIdx.y * nbx + blockIdx.x;
    if ((nwg & 7) == 0) id = (id & 7) * (nwg >> 3) + (id >> 3);
    const int bm = (id / nbx) * GBM, bn = (id % nbx) * GBN;

    const int wid = tid >> 6, lane = tid & 63;
    const int wm = (wid >> 1) * 64, wn = (wid & 1) * 64;
    const int l15 = lane & 15, g4 = lane >> 4;
    const size_t psA = (size_t)M * D_, psB = (size_t)N * D_;

    // per-lane staging descriptors (k-invariant): wave w owns slots [768w,768w+768)
    const unsigned short* gsrc[12];
    unsigned short* ldst[12];
#pragma unroll
    for (int q2 = 0; q2 < 12; ++q2) {
        int s  = wid * 768 + q2 * 64 + lane;
        int isB = (s >= 1536);
        int sl = isB ? (s - 1536) : s;
        int p  = sl >> 9;          // plane
        int rem = sl & 511;
        int r  = rem >> 2;         // tile row
        int cs = rem & 3;          // swizzled 16B k-chunk slot
        int c  = cs ^ ((r >> 1) & 3);   // source k-chunk (inverse swizzle)
        const unsigned short* bp = isB ? Bsp : Asp;
        size_t ps = isB ? psB : psA;
        int row = (isB ? bn : bm) + r;
        gsrc[q2] = bp + (size_t)p * ps + (size_t)row * D_ + c * 8;
        ldst[q2] = L + (wid * 768 + q2 * 64) * 8;   // slot*8 shorts (=16B)
    }
    // frag ds_read bases (shorts); swizzle const per lane: f((R+16i))==f(R)
    const int fA = ((wm + l15) >> 1) & 3;
    const int fB = ((wn + l15) >> 1) & 3;
    const unsigned short* aB = L + (wm + l15) * 32 + ((g4 ^ fA) * 8);
    const unsigned short* bB = L + 1536 * 8 + (wn + l15) * 32 + ((g4 ^ fB) * 8);

    f32x4 acc[4][4] = {};
    for (int k0 = 0; k0 < D_; k0 += GBK) {
        __syncthreads();               // prev-iter reads done before overwrite
#pragma unroll
        for (int q2 = 0; q2 < 12; ++q2)
            gld16(gsrc[q2] + k0, ldst[q2]);
        __syncthreads();               // drains vmcnt -> LDS tile ready
        short8v af[3][4], bf[3][4];
#pragma unroll
        for (int i = 0; i < 4; ++i)
#pragma unroll
            for (int p = 0; p < 3; ++p) {
                af[p][i] = *(const short8v*)(aB + p * 4096 + i * 512);
                bf[p][i] = *(const short8v*)(bB + p * 4096 + i * 512);
            }
#pragma unroll
        for (int i = 0; i < 4; ++i)
#pragma unroll
            for (int j = 0; j < 4; ++j) {
                acc[i][j] = __builtin_amdgcn_mfma_f32_16x16x32_bf16(af[0][i], bf[0][j], acc[i][j], 0, 0, 0);
                acc[i][j] = __builtin_amdgcn_mfma_f32_16x16x32_bf16(af[0][i], bf[1][j], acc[i][j], 0, 0, 0);
                acc[i][j] = __builtin_amdgcn_mfma_f32_16x16x32_bf16(af[1][i], bf[0][j], acc[i][j], 0, 0, 0);
                acc[i][j] = __builtin_amdgcn_mfma_f32_16x16x32_bf16(af[1][i], bf[1][j], acc[i][j], 0, 0, 0);
                acc[i][j] = __builtin_amdgcn_mfma_f32_16x16x32_bf16(af[0][i], bf[2][j], acc[i][j], 0, 0, 0);
                acc[i][j] = __builtin_amdgcn_mfma_f32_16x16x32_bf16(af[2][i], bf[0][j], acc[i][j], 0, 0, 0);
            }
    }
    // C/D layout: col = lane&15, row = (lane>>4)*4 + reg   [m89-verified]
#pragma unroll
    for (int i = 0; i < 4; ++i) {
        int gr0 = bm + wm + i * 16 + (lane >> 4) * 4;
#pragma unroll
        for (int j = 0; j < 4; ++j) {
            int gc = bn + wn + j * 16 + l15;
            float bv = bias ? bias[gc] : 0.f;
#pragma unroll
            for (int q = 0; q < 4; ++q) {
                float v = acc[i][j][q] + bv;
                if (doRelu) v = fmaxf(v, 0.f);
                C[(size_t)(gr0 + q) * N + gc] = v;
            }
        }
    }
}

__global__ __launch_bounds__(256) void k_topk_up(const float* __restrict__ big,
                                                 int* __restrict__ up_idx,
                                                 float* __restrict__ up_val) {
    __shared__ __attribute__((aligned(16))) float row[FUP];
    __shared__ unsigned hist[256];
    __shared__ int scratch[68];
    int b = blockIdx.x;
    const float4* s4 = (const float4*)(big + (size_t)b * FUP);
    float4* r4 = (float4*)row;
    for (int i = threadIdx.x; i < FUP / 4; i += 256) r4[i] = s4[i];
    __syncthreads();
    topk64_block(row, FUP, up_idx + b * 64, up_val + b * 64, hist, scratch);
}

// Counting-sort each fd's 256 connections into NPW fu-window buckets plus a
// dup bucket (index NPW). Output: ent_fu/ent_c (window-sorted per fd) and
// per-fd bucket offsets woff[fd][NPW+2] (last = 256).
__global__ __launch_bounds__(256) void k_sortwin(
    const int* __restrict__ conn, const int* __restrict__ mode_p,
    unsigned short* __restrict__ ent_fu, unsigned char* __restrict__ ent_c,
    unsigned short* __restrict__ woff)
{
    __shared__ int crow[CONN];
    __shared__ int cnt[NPW + 1];
    __shared__ int base[NPW + 1];
    __shared__ int cur[NPW + 1];
    int fd = blockIdx.x, tid = threadIdx.x;
    int mode = *mode_p;
    crow[tid] = getconn(conn, (size_t)fd * CONN + tid, mode);
    if (tid <= NPW) cnt[tid] = 0;
    __syncthreads();
    int fu = crow[tid];
    bool dup = false;
    for (int q = 0; q < tid; ++q) dup |= (crow[q] == fu);
    int win = dup ? NPW : (fu / PDW);
    atomicAdd(&cnt[win], 1);
    __syncthreads();
    if (tid == 0) {
        int run = 0;
        for (int i = 0; i <= NPW; ++i) { base[i] = run; run += cnt[i]; }
    }
    __syncthreads();
    if (tid <= NPW) {
        woff[fd * (NPW + 2) + tid] = (unsigned short)base[tid];
        cur[tid] = base[tid];
    }
    if (tid == 0) woff[fd * (NPW + 2) + NPW + 1] = (unsigned short)CONN;
    __syncthreads();
    int pos = atomicAdd(&cur[win], 1);
    ent_fu[(size_t)fd * CONN + pos] = (unsigned short)fu;
    ent_c[(size_t)fd * CONN + pos]  = (unsigned char)tid;
}

// pd[fd,c] = W_enc_down[fd]·W_dec_upT[fu]  via window-sorted entry lists.
// Grid (fd, window); window is the slow dim so co-resident blocks share one
// 3 MB WduT window (L2-resident). Fine-grained blocks (12288/window, ~1400
// concurrent) keep phase width ~0.1 windows -> no L2 thrash (pd4/pd5 lesson).
// Inner dot: 4 independent accumulator chains (pd3-verified body).
__global__ __launch_bounds__(256) void k_pd2(
    const float* __restrict__ Wdn, const float* __restrict__ WduT,
    const unsigned short* __restrict__ ent_fu, const unsigned char* __restrict__ ent_c,
    const unsigned short* __restrict__ woff, float* __restrict__ pd)
{
    __shared__ __attribute__((aligned(16))) float wrow[D_];
    int fd = blockIdx.x, win = blockIdx.y, tid = threadIdx.x;
    int s = woff[fd * (NPW + 2) + win];
    int e = woff[fd * (NPW + 2) + win + 1];
    if (win == NPW) {           // dup bucket: masked entries contribute 0
        for (int t = s + tid; t < e; t += 256)
            pd[(size_t)fd * CONN + ent_c[(size_t)fd * CONN + t]] = 0.f;
        return;
    }
    if (s == e) return;
    const float4* wsrc = (const float4*)(Wdn + (size_t)fd * D_);
    for (int i = tid; i < D_ / 4; i += 256) ((float4*)wrow)[i] = wsrc[i];
    __syncthreads();
    const int wave = tid >> 6, lane = tid & 63;
    const int grp = lane >> 4, gi = lane & 15;
    float4 wr[12];
#pragma unroll
    for (int j = 0; j < 12; ++j)
        wr[j] = *(const float4*)&wrow[gi * 4 + j * 64];
    for (int q = s + wave * 4; q < e; q += 16) {
        int idx = q + grp;
        bool act = idx < e;
        int idxc = act ? idx : (e - 1);
        int fu = ent_fu[(size_t)fd * CONN + idxc];
        const float* wu = WduT + (size_t)fu * D_;
        float s0 = 0.f, s1 = 0.f, s2 = 0.f, s3 = 0.f;
#pragma unroll
        for (int j = 0; j < 12; j += 4) {
            float4 u0 = *(const float4*)&wu[gi * 4 + (j + 0) * 64];
            float4 u1 = *(const float4*)&wu[gi * 4 + (j + 1) * 64];
            float4 u2 = *(const float4*)&wu[gi * 4 + (j + 2) * 64];
            float4 u3 = *(const float4*)&wu[gi * 4 + (j + 3) * 64];
            s0 = fmaf(u0.x, wr[j + 0].x, s0); s0 = fmaf(u0.y, wr[j + 0].y, s0);
            s0 = fmaf(u0.z, wr[j + 0].z, s0); s0 = fmaf(u0.w, wr[j + 0].w, s0);
            s1 = fmaf(u1.x, wr[j + 1].x, s1); s1 = fmaf(u1.y, wr[j + 1].y, s1);
            s1 = fmaf(u1.z, wr[j + 1].z, s1); s1 = fmaf(u1.w, wr[j + 1].w, s1);
            s2 = fmaf(u2.x, wr[j + 2].x, s2); s2 = fmaf(u2.y, wr[j + 2].y, s2);
            s2 = fmaf(u2.z, wr[j + 2].z, s2); s2 = fmaf(u2.w, wr[j + 2].w, s2);
            s3 = fmaf(u3.x, wr[j + 3].x, s3); s3 = fmaf(u3.y, wr[j + 3].y, s3);
            s3 = fmaf(u3.z, wr[j + 3].z, s3); s3 = fmaf(u3.w, wr[j + 3].w, s3);
        }
        float sacc = (s0 + s1) + (s2 + s3);
#pragma unroll
        for (int m = 1; m < 16; m <<= 1) sacc += __shfl_xor(sacc, m);
        if (act && gi == 0)
            pd[(size_t)fd * CONN + ent_c[(size_t)fd * CONN + idx]] = sacc;
    }
}

__global__ void k_hist(const int* __restrict__ conn, const int* __restrict__ mode_p,
                       unsigned* __restrict__ counts, int total) {
    int mode = *mode_p;
    for (int e = blockIdx.x * blockDim.x + threadIdx.x; e < total;
         e += gridDim.x * blockDim.x)
        atomicAdd(&counts[getconn(conn, (size_t)e, mode)], 1u);
}

__global__ void k_scan(const unsigned* __restrict__ counts,
                       unsigned* __restrict__ offsets, unsigned* __restrict__ cursor) {
    __shared__ unsigned sums[256];
    int tid = threadIdx.x;
    const int CH = FUP / 256;   // 48
    unsigned local = 0;
    for (int i = 0; i < CH; ++i) local += counts[tid * CH + i];
    sums[tid] = local;
    __syncthreads();
    for (int off = 1; off < 256; off <<= 1) {
        unsigned v = 0;
        if (tid >= off) v = sums[tid - off];
        __syncthreads();
        sums[tid] += v;
        __syncthreads();
    }
    unsigned run = (tid == 0) ? 0u : sums[tid - 1];
    for (int i = 0; i < CH; ++i) {
        int idx = tid * CH + i;
        offsets[idx] = run;
        cursor[idx]  = run;
        run += counts[idx];
    }
    if (tid == 255) offsets[FUP] = run;
}

__global__ void k_scatter(const int* __restrict__ conn, const int* __restrict__ mode_p,
                          const float* __restrict__ pd, unsigned* __restrict__ cursor,
                          unsigned short* __restrict__ rev_fd, float* __restrict__ rev_w,
                          int total) {
    int mode = *mode_p;
    for (int e = blockIdx.x * blockDim.x + threadIdx.x; e < total;
         e += gridDim.x * blockDim.x) {
        int fu = getconn(conn, (size_t)e, mode);
        unsigned pos = atomicAdd(&cursor[fu], 1u);
        rev_fd[pos] = (unsigned short)(e >> 8);   // fd = e / CONN
        rev_w[pos]  = pd[e];
    }
}

// per-batch-row: contributions scatter + combine + top-64 of approx
__global__ __launch_bounds__(256) void k_down(
    const float* __restrict__ big /*approx0*/, const float* __restrict__ ln_scale,
    const float* __restrict__ c_in, const float* __restrict__ c_out,
    const int* __restrict__ up_idx, const float* __restrict__ up_val,
    const unsigned* __restrict__ offsets, const unsigned short* __restrict__ rev_fd,
    const float* __restrict__ rev_w, int* __restrict__ down_idx,
    float* __restrict__ down_val)
{
    __shared__ __attribute__((aligned(16))) float contrib[FDN];
    __shared__ unsigned hist[256];
    __shared__ int scratch[68];
    int b = blockIdx.x, tid = threadIdx.x;
    float4* c4 = (float4*)contrib;
    for (int i = tid; i < FDN / 4; i += 256) c4[i] = make_float4(0.f, 0.f, 0.f, 0.f);
    __syncthreads();
    for (int j = 0; j < KTOP; ++j) {
        int fu = up_idx[b * 64 + j];
        float v = up_val[b * 64 + j];
        unsigned s = offsets[fu], e = offsets[fu + 1];
        for (unsigned t = s + tid; t < e; t += 256)
            atomicAdd(&contrib[rev_fd[t]], v * rev_w[t]);
    }
    __syncthreads();
    float ls = ln_scale[b];
    const float* ap = big + (size_t)b * FDN;
    for (int i = tid; i < FDN; i += 256)
        contrib[i] = (ap[i] + contrib[i] + c_in[i]) / ls + c_out[i];
    __syncthreads();
    topk64_block(contrib, FDN, down_idx + b * 64, down_val + b * 64, hist, scratch);
}

__global__ __launch_bounds__(256) void k_decode(
    const int* __restrict__ down_idx, const float* __restrict__ down_val,
    const float* __restrict__ WddT, const float* __restrict__ b_dec_down,
    float* __restrict__ out)
{
    __shared__ int fidx[64];
    __shared__ float fval[64];
    int b = blockIdx.x, tid = threadIdx.x;
    if (tid < 64) { fidx[tid] = down_idx[b * 64 + tid]; fval[tid] = down_val[b * 64 + tid]; }
    __syncthreads();
    float a0 = b_dec_down[tid], a1 = b_dec_down[tid + 256], a2 = b_dec_down[tid + 512];
    for (int j = 0; j < 64; ++j) {
        const float* r = WddT + (size_t)fidx[j] * D_;
        float v = fval[j];
        a0 += v * r[tid];
        a1 += v * r[tid + 256];
        a2 += v * r[tid + 512];
    }
    float* o = out + (size_t)b * D_;
    o[tid] = a0; o[tid + 256] = a1; o[tid + 512] = a2;
}

// ---------------------------------------------------------------- launch

extern "C" void kernel_launch(void* const* d_in, const int* in_sizes, int n_in,
                              void* d_out, int out_size, void* d_ws, size_t ws_size,
                              hipStream_t stream)
{
    const float* initial_acts = (const float*)d_in[0];
    const float* x_up         = (const float*)d_in[1];
    const float* ln_scale     = (const float*)d_in[2];
    const float* W_enc_up     = (const float*)d_in[3];
    const float* b_enc_up     = (const float*)d_in[4];
    const float* b_dec_up     = (const float*)d_in[5];
    const float* W_dec_up     = (const float*)d_in[6];
    const float* W_enc_down   = (const float*)d_in[7];
    const float* b_enc_down   = (const float*)d_in[8];
    const float* b_dec_down   = (const float*)d_in[9];
    const float* W_dec_down   = (const float*)d_in[10];
    const int*   conn         = (const int*)d_in[11];
    float* out = (float*)d_out;

    // ---- workspace layout (~132.7 MB of 128 MiB = 134.2 MB) ----
    // region 0 (bigU, 50,331,648 B): phase1 big[1024x12288] f32; then
    //   pd(12.58M)+ent_fu(6.29M)+ent_c(3.15M)+woff(0.34M); then phase2 big[512x12288]
    // region Bsplit (56,623,104 B): phase1 Wup 3xbf16 planes; then WduT f32
    //   (37.7M); then Wdn 3xbf16 planes; then WddT f32
    // Asplit1 (phase1, 4.72M) overlaps rev_w (rev_w written only after phase1)
    char* w = (char*)d_ws;
    float*          big      = (float*)(w);
    float*          pd       = (float*)(w);                          // after phase1
    unsigned short* ent_fu   = (unsigned short*)(w + 12582912);
    unsigned char*  ent_c    = (unsigned char*) (w + 18874368);
    unsigned short* woff     = (unsigned short*)(w + 22020096);      // ends 22,364,160
    unsigned short* Bsplit   = (unsigned short*)(w + 50331648);      // 56,623,104 B
    float*          Wt       = (float*)(w + 50331648);               // alias (WduT/WddT)
    float*          rev_w    = (float*)(w + 106954752);              // 12,582,912 B
    unsigned short* Asplit1  = (unsigned short*)(w + 106954752);     // phase1 alias
    unsigned short* rev_fd   = (unsigned short*)(w + 119537664);     // 6,291,456 B
    unsigned short* Asplit2  = (unsigned short*)(w + 125829120);     // 2,359,296 B
    int*            up_idx   = (int*)  (w + 128188416);              // 1 MiB
    float*          up_val   = (float*)(w + 129236992);              // 1 MiB
    int*            down_idx = (int*)  (w + 130285568);              // 1 MiB
    float*          down_val = (float*)(w + 131334144);              // 1 MiB
    unsigned*       offsets  = (unsigned*)(w + 132382720);           // 64 KiB
    unsigned*       cursor   = (unsigned*)(w + 132448256);           // 64 KiB
    unsigned*       counts   = (unsigned*)(w + 132513792);           // 64 KiB
    float*          bias_up  = (float*)(w + 132579328);              // 48 KiB
    float*          c_in     = (float*)(w + 132628480);              // 48 KiB
    float*          c_out    = (float*)(w + 132677632);              // 48 KiB
    int*            mode_p   = (int*)  (w + 132726784);
    // ends ~132,726,848 B

    const int total_conn = FDN * CONN;
    dim3 tb(32, 8);

    k_detect<<<1, 64, 0, stream>>>(conn, mode_p);
    k_precompute<<<FUP / 4, 256, 0, stream>>>(W_enc_up, W_enc_down, b_enc_up, b_enc_down,
                                              b_dec_up, b_dec_down, bias_up, c_in, c_out);
    // phase 1: pre_up = relu(x_up @ W_enc_up^T + bias_up), then top-64, per chunk
    k_split3<<<FUP * D_ / 2048, 256, 0, stream>>>(W_enc_up, Bsplit, FUP);
    for (int c = 0; c < NCH; ++c) {
        k_split3<<<CHUNK * D_ / 2048, 256, 0, stream>>>(x_up + (size_t)c * CHUNK * D_,
                                                        Asplit1, CHUNK);
        k_gemm_mfma<<<dim3(FUP / GBN, CHUNK / GBM), 256, 0, stream>>>(
            Asplit1, Bsplit, big, bias_up, CHUNK, FUP, 1);
        k_topk_up<<<CHUNK, 256, 0, stream>>>(big, up_idx + (size_t)c * CHUNK * 64,
                                             up_val + (size_t)c * CHUNK * 64);
    }
    // WduT into Bsplit region (Wup splits dead); ent into big region (big dead)
    k_transpose<<<dim3(FUP / 32, D_ / 32), tb, 0, stream>>>(W_dec_up, Wt, D_, FUP);
    k_sortwin<<<FDN, 256, 0, stream>>>(conn, mode_p, ent_fu, ent_c, woff);
    k_pd2<<<dim3(FDN, NPW + 1), 256, 0, stream>>>(W_enc_down, Wt, ent_fu, ent_c, woff, pd);
    k_zero<<<48, 256, 0, stream>>>(counts, FUP);
    k_hist<<<4096, 256, 0, stream>>>(conn, mode_p, counts, total_conn);
    k_scan<<<1, 256, 0, stream>>>(counts, offsets, cursor);
    k_scatter<<<4096, 256, 0, stream>>>(conn, mode_p, pd, cursor, rev_fd, rev_w, total_conn);
    // phase 2: approx0 = initial_acts @ W_enc_down^T, combine + top-64, per CH2 chunk
    k_split3<<<FDN * D_ / 2048, 256, 0, stream>>>(W_enc_down, Bsplit, FDN);
    for (int c = 0; c < NCH2; ++c) {
        k_split3<<<CH2 * D_ / 2048, 256, 0, stream>>>(initial_acts + (size_t)c * CH2 * D_,
                                                      Asplit2, CH2);
        k_gemm_mfma<<<dim3(FDN / GBN, CH2 / GBM), 256, 0, stream>>>(
            Asplit2, Bsplit, big, nullptr, CH2, FDN, 0);
        k_down<<<CH2, 256, 0, stream>>>(big, ln_scale + (size_t)c * CH2, c_in, c_out,
                                        up_idx + (size_t)c * CH2 * 64,
                                        up_val + (size_t)c * CH2 * 64,
                                        offsets, rev_fd, rev_w,
                                        down_idx + (size_t)c * CH2 * 64,
                                        down_val + (size_t)c * CH2 * 64);
    }
    // WddT into Bsplit region (Wdn splits dead after last GEMM2)
    k_transpose<<<dim3(FDN / 32, D_ / 32), tb, 0, stream>>>(W_dec_down, Wt, D_, FDN);
    k_decode<<<B_, 256, 0, stream>>>(down_idx, down_val, Wt, b_dec_down, out);
}